// Round 11
// baseline (227.291 us; speedup 1.0000x reference)
//
#include <hip/hip_runtime.h>
#include <stdint.h>

// ---------------------------------------------------------------------------
// MixingLayer: b=16, m=64, f=128, k=64, L2=16, LMAX=4. ALL I/O IS FP32.
// SEG = [0,1,1,1,2,2,2,2,2,3,3,3,3,3,3,3]
//
// Round-11: BARRIER-FREE wave-autonomous fused GEMM.
//   * Each wave owns 32m x 128n; G staged in wave-PRIVATE LDS slot
//     (producer == consumer wave -> lgkmcnt ordering only, NO s_barrier
//     anywhere in the K-loop; wave slip across the CU hides latency).
//   * B read straight from pre-converted bf16 Wb into VGPRs (16B/lane per
//     n-tile = exact b-fragment; no LDS, no in-loop conversion); Wp[j]
//     rotated: reloaded for t+1 right after MFMA j consumes it.
//   * y prefetched 1 step ahead; packed via v_perm (1 op / 2 values).
//   * grid (128, 8), linear%8 = g_id%8 -> mtile-siblings share an XCD,
//     so each g_id's 32KB Wb slab is L2-hot.
//
// ws layout (bytes):
//   Wb    bf16 [128 n][65536 kk]       @ 0          (16,777,216)
//   Cpart bf16 [128 sp][1024 bm][128n] @ 16777216   (33,554,432)
//   wfT   f32  [2][64 k][4 l][128 f]   @ 50331648   (   262,144)
// ---------------------------------------------------------------------------

typedef __bf16 bf16x8 __attribute__((ext_vector_type(8)));
typedef float f32x4 __attribute__((ext_vector_type(4)));

__device__ __forceinline__ uint16_t f2b(float f) {
  uint32_t u = __float_as_uint(f);
  u += 0x7fffu + ((u >> 16) & 1u);   // RNE
  return (uint16_t)(u >> 16);
}
__device__ __forceinline__ float b2f(uint16_t u) {
  return __uint_as_float((uint32_t)u << 16);
}
__device__ __forceinline__ uint32_t pk2(float a, float b) {  // RNE pack
  return (uint32_t)f2b(a) | ((uint32_t)f2b(b) << 16);
}
#if __has_builtin(__builtin_amdgcn_perm)
__device__ __forceinline__ uint32_t pkt(uint32_t lo, uint32_t hi) {
  return __builtin_amdgcn_perm(hi, lo, 0x07060302u);  // {hi16(hi),hi16(lo)}
}
#else
__device__ __forceinline__ uint32_t pkt(uint32_t lo, uint32_t hi) {
  return (lo >> 16) | (hi & 0xffff0000u);
}
#endif

#if __has_builtin(__builtin_amdgcn_fdot2_f32_bf16)
typedef __bf16 bf16x2 __attribute__((ext_vector_type(2)));
__device__ __forceinline__ float dot2b(uint32_t a, uint32_t b, float c) {
  union { uint32_t u; bf16x2 v; } ua, ub;
  ua.u = a; ub.u = b;
  return __builtin_amdgcn_fdot2_f32_bf16(ua.v, ub.v, c, false);
}
#else
__device__ __forceinline__ float dot2b(uint32_t a, uint32_t b, float c) {
  float a0 = __uint_as_float(a << 16), a1 = __uint_as_float(a & 0xffff0000u);
  float b0 = __uint_as_float(b << 16), b1 = __uint_as_float(b & 0xffff0000u);
  return c + a0 * b0 + a1 * b1;
}
#endif

// ---------------------------------------------------------------------------
// K0: blocks [0,4096): Wb = bf16(wx0|wy0); blocks [4096,4128): wfT transpose.
// ---------------------------------------------------------------------------
__global__ __launch_bounds__(256) void convert_kernel(
    const float* __restrict__ wx0, const float* __restrict__ wy0,
    const float* __restrict__ wxf, const float* __restrict__ wyf,
    uint16_t* __restrict__ Wb, float* __restrict__ wfT) {
  if (blockIdx.x < 4096) {
    size_t i = ((size_t)blockIdx.x * 256 + threadIdx.x) * 8;
    const float* s = (i < 4194304) ? (wx0 + i) : (wy0 + (i - 4194304));
    float4 v0 = *(const float4*)s;
    float4 v1 = *(const float4*)(s + 4);
    *(uint4*)(Wb + i) = make_uint4(pk2(v0.x, v0.y), pk2(v0.z, v0.w),
                                   pk2(v1.x, v1.y), pk2(v1.z, v1.w));
  } else {
    int base = (blockIdx.x - 4096) * 2048 + threadIdx.x * 8;
#pragma unroll
    for (int ii = 0; ii < 8; ++ii) {
      int idx = base + ii;
      int side = idx >> 15, rem = idx & 32767;
      int k = rem >> 9, l = (rem >> 7) & 3, f = rem & 127;
      const float* src = side ? wyf : wxf;
      wfT[idx] = src[((size_t)l * 128 + f) * 64 + k];
    }
  }
}

// ---------------------------------------------------------------------------
// K1: barrier-free fused G-gen + split GEMM.
// grid (128, 8): g_id -> fb = g>>3 (8 fx), fyg = g&7 (16 fy); y = M-tile.
// 16 steps, step t: fy = fyg*16+t, kk = fy*512 + FB*4 + [0,32).
// Wave wid owns m rows [wid*32, wid*32+32), all 128 n.
// ---------------------------------------------------------------------------
__global__ __launch_bounds__(256) void fused_gemm(
    const float* __restrict__ x, const float* __restrict__ y,
    const uint16_t* __restrict__ Wb, uint16_t* __restrict__ Cpart) {
  // K-loop: wave-private A slots, wave wid at elements [wid*2560, +2560)
  // (2 slots x 1280 = 32 rows x 40 pad). Epilogue: full 16384 (32 KB).
  __shared__ __align__(16) uint16_t smem[16384];

  int tid = threadIdx.x;
  int wid = tid >> 6, lane = tid & 63;
  int g_id = blockIdx.x;
  int fb = g_id >> 3, fyg = g_id & 7;
  int FB = fb * 8, fy0 = fyg * 16;
  int m0 = blockIdx.y * 128;
  int r = lane & 15, q = lane >> 4;
  int mw = lane & 31, halfw = lane >> 5;
  int mrow = m0 + wid * 32 + mw;

  const float* xrow = x + (size_t)mrow * 2048 + (FB + halfw * 4) * 16;
  const float* yrow = y + (size_t)mrow * 2048 + fy0 * 16;
  // b-fragment source: row j*16+r, col (fy0+t)*512 + FB*4 + q*8 (16B aligned)
  const uint16_t* wlane = Wb + (size_t)r * 65536 + (size_t)fy0 * 512 + FB * 4 + q * 8;

  // ---- prologue: issue x (64 B/lane), W(0) (8x16B), y(0) (64 B)
  float4 xv[16];
#pragma unroll
  for (int p = 0; p < 16; ++p) xv[p] = *(const float4*)(xrow + p * 4);
  uint4 Wp[8];
#pragma unroll
  for (int j = 0; j < 8; ++j)
    Wp[j] = *(const uint4*)(wlane + (size_t)j * 1048576);
  float4 Yv[4];
#pragma unroll
  for (int p = 0; p < 4; ++p) Yv[p] = *(const float4*)(yrow + p * 4);

  uint32_t xr[32];   // x packed bf16 (RNE, one-time)
#pragma unroll
  for (int fxp = 0; fxp < 4; ++fxp)
#pragma unroll
    for (int cc = 0; cc < 4; ++cc) {
      float4 v = xv[fxp * 4 + cc];
      xr[fxp * 8 + cc * 2 + 0] = pk2(v.x, v.y);
      xr[fxp * 8 + cc * 2 + 1] = pk2(v.z, v.w);
    }

  f32x4 zero = {0.f, 0.f, 0.f, 0.f};
  f32x4 acc[2][8];
#pragma unroll
  for (int i = 0; i < 2; ++i)
#pragma unroll
    for (int j = 0; j < 8; ++j) acc[i][j] = zero;

  int slot = wid * 2560;

  for (int t = 0; t < 16; ++t) {
    // ---- pack y(t) (perm truncation: 1 op / 2 values)
    uint32_t yq[8];
    yq[0] = pkt(__float_as_uint(Yv[0].x), __float_as_uint(Yv[0].y));
    yq[1] = pkt(__float_as_uint(Yv[0].z), __float_as_uint(Yv[0].w));
    yq[2] = pkt(__float_as_uint(Yv[1].x), __float_as_uint(Yv[1].y));
    yq[3] = pkt(__float_as_uint(Yv[1].z), __float_as_uint(Yv[1].w));
    yq[4] = pkt(__float_as_uint(Yv[2].x), __float_as_uint(Yv[2].y));
    yq[5] = pkt(__float_as_uint(Yv[2].z), __float_as_uint(Yv[2].w));
    yq[6] = pkt(__float_as_uint(Yv[3].x), __float_as_uint(Yv[3].y));
    yq[7] = pkt(__float_as_uint(Yv[3].z), __float_as_uint(Yv[3].w));
    // ---- issue y(t+1): in flight across the rest of this step
    if (t < 15) {
      const float* yp = yrow + (size_t)(t + 1) * 16;
#pragma unroll
      for (int p = 0; p < 4; ++p) Yv[p] = *(const float4*)(yp + p * 4);
    }
    // ---- G-gen: 40 dot2b -> gg[16] (lane: m=mw, fx=FB+halfw*4+fxp, l=0..3)
    uint32_t yl0 = yq[0] & 0xffffu, yh0 = yq[0] & 0xffff0000u;
    uint32_t yl4 = yq[4] & 0xffffu, yh4 = yq[4] & 0xffff0000u;
    float gg[16];
#pragma unroll
    for (int fxp = 0; fxp < 4; ++fxp) {
      const uint32_t* xp = xr + fxp * 8;
      gg[fxp * 4 + 0] = dot2b(xp[0], yl0, 0.f);
      gg[fxp * 4 + 1] = dot2b(xp[1], yq[1], dot2b(xp[0], yh0, 0.f));
      gg[fxp * 4 + 2] = dot2b(xp[4], yl4,
                          dot2b(xp[3], yq[3], dot2b(xp[2], yq[2], 0.f)));
      gg[fxp * 4 + 3] = dot2b(xp[7], yq[7], dot2b(xp[6], yq[6],
                          dot2b(xp[5], yq[5], dot2b(xp[4], yh4, 0.f))));
    }
    // ---- pack G (RNE) -> wave-private LDS slot (t&1)
    int ab = slot + (t & 1) * 1280;
    {
      uint32_t go[8];
#pragma unroll
      for (int p = 0; p < 8; ++p) go[p] = pk2(gg[2 * p], gg[2 * p + 1]);
      uint16_t* ad = &smem[ab + mw * 40 + halfw * 16];
      *(uint4*)ad       = make_uint4(go[0], go[1], go[2], go[3]);
      *(uint4*)(ad + 8) = make_uint4(go[4], go[5], go[6], go[7]);
    }
    // ---- a-fragments (same wave wrote them; compiler inserts lgkmcnt wait)
    bf16x8 a0 = *(const bf16x8*)&smem[ab + r * 40 + q * 8];
    bf16x8 a1 = *(const bf16x8*)&smem[ab + (16 + r) * 40 + q * 8];
    // ---- 16 MFMA; rotate Wp[j] to t+1 right after consumption
#pragma unroll
    for (int j = 0; j < 8; ++j) {
      union { uint4 u; bf16x8 v; } bb;
      bb.u = Wp[j];
      acc[0][j] = __builtin_amdgcn_mfma_f32_16x16x32_bf16(a0, bb.v, acc[0][j], 0, 0, 0);
      acc[1][j] = __builtin_amdgcn_mfma_f32_16x16x32_bf16(a1, bb.v, acc[1][j], 0, 0, 0);
      if (t < 15)
        Wp[j] = *(const uint4*)(wlane + (size_t)j * 1048576 + (size_t)(t + 1) * 512);
    }
    // NO barrier: LDS slot is wave-private, W/y are VGPR-resident.
  }

  // ---- epilogue: C tile -> LDS (bf16) -> coalesced global stores
  __syncthreads();   // waves slip in the K-loop; resync before smem reuse
#pragma unroll
  for (int i = 0; i < 2; ++i)
#pragma unroll
    for (int j = 0; j < 8; ++j)
#pragma unroll
      for (int reg = 0; reg < 4; ++reg) {
        int mm = wid * 32 + i * 16 + q * 4 + reg;
        int nn = j * 16 + r;
        smem[mm * 128 + nn] = f2b(acc[i][j][reg]);
      }
  __syncthreads();
  {
    int row = tid >> 1, ch = tid & 1;
    const uint16_t* csrc = &smem[row * 128 + ch * 64];
    uint16_t* cdst = Cpart + (size_t)g_id * 131072 +
                     (size_t)(m0 + row) * 128 + ch * 64;
#pragma unroll
    for (int kkk = 0; kkk < 8; ++kkk)
      *(uint4*)(cdst + kkk * 8) = *(const uint4*)(csrc + kkk * 8);
  }
}

// ---------------------------------------------------------------------------
// K2: ONE BLOCK PER bm: reduce 128 bf16 partials, 2 MLP stages
// (bias[st][m][j], m=bm&63), gates via wfT, fused elementwise output.
// ---------------------------------------------------------------------------
__global__ __launch_bounds__(256) void finish_kernel(
    const float* __restrict__ x, const float* __restrict__ y,
    const float* __restrict__ wx_mlp, const float* __restrict__ bx_mlp,
    const float* __restrict__ wy_mlp, const float* __restrict__ by_mlp,
    const float* __restrict__ wfT,
    const uint16_t* __restrict__ Cpart, float* __restrict__ out) {
  const int seg[16] = {0,1,1,1,2,2,2,2,2,3,3,3,3,3,3,3};
  __shared__ float sred[256];
  __shared__ float sm[128];
  __shared__ float sg[2][128][4];
  int t = threadIdx.x;
  int bm = blockIdx.x;
  int mi = bm & 63;

  {  // split-K reduce: 256 threads, each sums 64 of the 128 bf16 partials
    int col = t & 127, hh = t >> 7;
    float s = 0.f;
#pragma unroll 8
    for (int sp = hh * 64; sp < hh * 64 + 64; ++sp)
      s += b2f(Cpart[(size_t)sp * 131072 + (size_t)bm * 128 + col]);
    sred[t] = s;
  }
  __syncthreads();
  if (t < 128) sm[t] = sred[t] + sred[t + 128];  // [0:64)=mx, [64:128)=my
  __syncthreads();

  for (int st = 0; st < 2; ++st) {
    float v = 0.f;
    if (t < 128) {
      int side = t >> 6, j = t & 63;
      const float* wmlp = side ? wy_mlp : wx_mlp;
      const float* bmlp = side ? by_mlp : bx_mlp;
      const float* mv = sm + side * 64;
#pragma unroll 8
      for (int k = 0; k < 64; ++k)
        v += mv[k] * wmlp[(st * 64 + k) * 64 + j];
      v += bmlp[(st * 64 + mi) * 64 + j];
      v = v / (1.f + __expf(-v));
    }
    __syncthreads();
    if (t < 128) sm[t] = v;
    __syncthreads();
  }

  {  // gates: side wave-uniform, coalesced wfT reads
    int side = t >> 7, f = t & 127;
    const float* base = wfT + side * 32768;  // [k][l][f]
    const float* mv = sm + side * 64;
    float gg[4] = {0.f, 0.f, 0.f, 0.f};
#pragma unroll 8
    for (int k = 0; k < 64; ++k) {
      float m2 = mv[k];
#pragma unroll
      for (int l = 0; l < 4; ++l)
        gg[l] += m2 * base[(k * 4 + l) * 128 + f];
    }
#pragma unroll
    for (int l = 0; l < 4; ++l)
      sg[side][f][l] = gg[l] / (1.f + __expf(-gg[l]));
  }
  __syncthreads();

  {  // output: thread -> (f, half), 8 floats; fully coalesced
    int f = t >> 1, half = t & 1;
    size_t base = ((size_t)bm * 128 + f) * 16 + half * 8;
    float4 xa = *(const float4*)(x + base), xb4 = *(const float4*)(x + base + 4);
    float4 ya = *(const float4*)(y + base), yb4 = *(const float4*)(y + base + 4);
    float xv[8] = {xa.x, xa.y, xa.z, xa.w, xb4.x, xb4.y, xb4.z, xb4.w};
    float yv[8] = {ya.x, ya.y, ya.z, ya.w, yb4.x, yb4.y, yb4.z, yb4.w};
    float o[8];
#pragma unroll
    for (int ii = 0; ii < 8; ++ii) {
      int c = half * 8 + ii;
      o[ii] = sg[0][f][seg[c]] * xv[ii] + sg[1][f][seg[c]] * yv[ii];
    }
    *(float4*)(out + base)     = make_float4(o[0], o[1], o[2], o[3]);
    *(float4*)(out + base + 4) = make_float4(o[4], o[5], o[6], o[7]);
  }
}

// ---------------------------------------------------------------------------
extern "C" void kernel_launch(void* const* d_in, const int* in_sizes, int n_in,
                              void* d_out, int out_size, void* d_ws, size_t ws_size,
                              hipStream_t stream) {
  const float* x      = (const float*)d_in[0];
  const float* y      = (const float*)d_in[1];
  const float* wx0    = (const float*)d_in[2];
  const float* wy0    = (const float*)d_in[3];
  const float* wx_mlp = (const float*)d_in[4];
  const float* bx_mlp = (const float*)d_in[5];
  const float* wy_mlp = (const float*)d_in[6];
  const float* by_mlp = (const float*)d_in[7];
  const float* wxf    = (const float*)d_in[8];
  const float* wyf    = (const float*)d_in[9];
  float* out = (float*)d_out;

  uint16_t* Wb    = (uint16_t*)d_ws;                               // 16,777,216 B
  uint16_t* Cpart = (uint16_t*)((char*)d_ws + (size_t)16777216);   // 33,554,432 B
  float*    wfT   = (float*)((char*)d_ws + (size_t)50331648);      //    262,144 B

  convert_kernel<<<4128, 256, 0, stream>>>(wx0, wy0, wxf, wyf, Wb, wfT);
  fused_gemm<<<dim3(128, 8), 256, 0, stream>>>(x, y, Wb, Cpart);
  finish_kernel<<<1024, 256, 0, stream>>>(x, y, wx_mlp, bx_mlp, wy_mlp, by_mlp,
                                          wfT, Cpart, out);
}